// Round 2
// baseline (394.542 us; speedup 1.0000x reference)
//
#include <hip/hip_runtime.h>
#include <cstddef>
#include <cstdint>

#define F_IN 128
#define D1   256   // HEADS*HID
#define HEADS 4
#define HID   64
#define OUT_C 32
#define NEG   0.2f

typedef unsigned short ushort_t;
typedef __attribute__((ext_vector_type(8))) short short8;
typedef __attribute__((ext_vector_type(4))) float f32x4;
typedef __attribute__((ext_vector_type(4))) unsigned short ushort4v;

__device__ __forceinline__ float bu2f(ushort_t u) {
  return __uint_as_float(((unsigned)u) << 16);
}
__device__ __forceinline__ ushort_t f2bu(float f) {
  unsigned u = __float_as_uint(f);
  return (ushort_t)((u + 0x7FFF + ((u >> 16) & 1)) >> 16);   // RNE
}

// ---- weight prep (fused): Bt[nn][k] = concat(Wl,Wr)^T in bf16, both layers ----
__global__ void prep_k(const float* __restrict__ Wl1, const float* __restrict__ Wr1,
                       const float* __restrict__ bl1, const float* __restrict__ br1,
                       ushort_t* __restrict__ Bt1, float* __restrict__ bias1c,
                       const float* __restrict__ Wl2, const float* __restrict__ Wr2,
                       const float* __restrict__ bl2, const float* __restrict__ br2,
                       ushort_t* __restrict__ Bt2, float* __restrict__ bias2c) {
  int b = blockIdx.x;
  if (b < 256) {           // layer 1: 512 x 128
    int i = b * 256 + threadIdx.x;
    int nn = i >> 7, k = i & 127;
    float v = (nn < D1) ? Wl1[(size_t)k * D1 + nn] : Wr1[(size_t)k * D1 + (nn - D1)];
    Bt1[(size_t)nn * F_IN + k] = f2bu(v);
    if (k == 0) bias1c[nn] = (nn < D1) ? bl1[nn] : br1[nn - D1];
  } else {                 // layer 2: 64 x 256
    int i = (b - 256) * 256 + threadIdx.x;
    int nn = i >> 8, k = i & 255;
    float v = (nn < OUT_C) ? Wl2[(size_t)k * OUT_C + nn] : Wr2[(size_t)k * OUT_C + (nn - OUT_C)];
    Bt2[(size_t)nn * D1 + k] = f2bu(v);
    if (k == 0) bias2c[nn] = (nn < OUT_C) ? bl2[nn] : br2[nn - OUT_C];
  }
}

// ---- layer-1 GEMM: C[M,512] = bf16(x[M,128] @ Bt1[512,128]^T + bias) ----
// One block per 128-row M-tile. Full K=128 A-tile staged ONCE in LDS
// (34.8 KB, one barrier); the 4 N-panels loop in-register with B fragments
// read straight from global (Bt1 = 128 KB, L2-resident). A is fetched from
// HBM exactly once -> no cross-XCD A-tile refetch.
__global__ __launch_bounds__(256, 4) void gemm1_k(
    const float* __restrict__ x, const ushort_t* __restrict__ Bt,
    const float* __restrict__ biasc, ushort_t* __restrict__ C, int M) {
  constexpr int LD = F_IN + 8;                 // 136 shorts -> 2-way max aliasing
  __shared__ ushort_t As[128][LD];
  const int tid = threadIdx.x;
  const int wave = tid >> 6, lane = tid & 63;
  const int wm = wave & 1, wn = wave >> 1;     // 2x2 wave grid over 128x128
  const int quad = lane >> 4, l16 = lane & 15;
  const int m0 = blockIdx.x * 128;
  // stage A: fp32 -> bf16, 8 chunks of short8 per thread
#pragma unroll
  for (int it = 0; it < 8; ++it) {
    int i = it * 256 + tid;
    int r = i >> 4, ch = i & 15;
    int gr = m0 + r;
    f32x4 v0 = {}, v1 = {};
    if (gr < M) {
      const float* p = x + (size_t)gr * F_IN + ch * 8;
      v0 = *(const f32x4*)p;
      v1 = *(const f32x4*)(p + 4);
    }
    short8 o;
    o[0] = (short)f2bu(v0[0]); o[1] = (short)f2bu(v0[1]);
    o[2] = (short)f2bu(v0[2]); o[3] = (short)f2bu(v0[3]);
    o[4] = (short)f2bu(v1[0]); o[5] = (short)f2bu(v1[1]);
    o[6] = (short)f2bu(v1[2]); o[7] = (short)f2bu(v1[3]);
    *(short8*)(&As[r][ch * 8]) = o;
  }
  __syncthreads();
  const ushort_t* Bw = Bt + (size_t)(wn * 64 + l16) * F_IN + quad * 8;
#pragma unroll
  for (int panel = 0; panel < 4; ++panel) {
    const ushort_t* Bp = Bw + (size_t)panel * 128 * F_IN;
    const int nbase = panel * 128 + wn * 64;
    float bv[4];
#pragma unroll
    for (int ni = 0; ni < 4; ++ni) bv[ni] = biasc[nbase + ni * 16 + l16];
    f32x4 acc[4][4] = {};
#pragma unroll
    for (int ks = 0; ks < 4; ++ks) {
      short8 af[4], bfr[4];
#pragma unroll
      for (int ni = 0; ni < 4; ++ni)
        bfr[ni] = *(const short8*)(Bp + (size_t)ni * 16 * F_IN + ks * 32);
#pragma unroll
      for (int mi = 0; mi < 4; ++mi)
        af[mi] = *(const short8*)(&As[wm * 64 + mi * 16 + l16][ks * 32 + quad * 8]);
#pragma unroll
      for (int mi = 0; mi < 4; ++mi)
#pragma unroll
        for (int ni = 0; ni < 4; ++ni)
          acc[mi][ni] = __builtin_amdgcn_mfma_f32_16x16x32_bf16(af[mi], bfr[ni],
                                                                acc[mi][ni], 0, 0, 0);
    }
    // epilogue for this panel; C/D layout: row = quad*4 + r, col = l16
#pragma unroll
    for (int mi = 0; mi < 4; ++mi) {
#pragma unroll
      for (int r = 0; r < 4; ++r) {
        int grow = m0 + wm * 64 + mi * 16 + quad * 4 + r;
        if (grow >= M) continue;
#pragma unroll
        for (int ni = 0; ni < 4; ++ni) {
          int gcol = nbase + ni * 16 + l16;
          C[(size_t)grow * 512 + gcol] = f2bu(acc[mi][ni][r] + bv[ni]);
        }
      }
    }
  }
}

// ---- bf16 MFMA GEMM (NT) for layer 2: C[M,N] = bf16(A[M,K] @ Bt[N,K]^T + bias) ----
template <int WM, int WN, int BK, bool CVT>
__global__ void mfma_gemm(const void* __restrict__ Av, const ushort_t* __restrict__ Bt,
                          const float* __restrict__ biasc, ushort_t* __restrict__ C,
                          int M, int N, int K) {
  constexpr int BM = WM * 64, BN = WN * 64;
  constexpr int LD = BK + 8;
  constexpr int CPR = BK / 8;           // 8-elem chunks per row
  __shared__ ushort_t As[BM][LD];
  __shared__ ushort_t Bs[BN][LD];
  const int tid = threadIdx.x;
  const int wave = tid >> 6, lane = tid & 63;
  const int wm = wave % WM, wn = wave / WM;
  const int quad = lane >> 4, l16 = lane & 15;
  const int m0 = blockIdx.y * BM, n0 = blockIdx.x * BN;
  const int nth = WM * WN * 64;
  f32x4 acc[4][4] = {};
  for (int k0 = 0; k0 < K; k0 += BK) {
    for (int i = tid; i < BM * CPR; i += nth) {
      int r = i / CPR, ch = i % CPR;
      int gr = m0 + r;
      if (CVT) {
        const float* A32 = (const float*)Av;
        f32x4 v0 = {}, v1 = {};
        if (gr < M) {
          const float* p = A32 + (size_t)gr * K + k0 + ch * 8;
          v0 = *(const f32x4*)p;
          v1 = *(const f32x4*)(p + 4);
        }
        short8 o;
        o[0] = (short)f2bu(v0[0]); o[1] = (short)f2bu(v0[1]);
        o[2] = (short)f2bu(v0[2]); o[3] = (short)f2bu(v0[3]);
        o[4] = (short)f2bu(v1[0]); o[5] = (short)f2bu(v1[1]);
        o[6] = (short)f2bu(v1[2]); o[7] = (short)f2bu(v1[3]);
        *(short8*)(&As[r][ch * 8]) = o;
      } else {
        const ushort_t* A16 = (const ushort_t*)Av;
        short8 v = {};
        if (gr < M) v = *(const short8*)(A16 + (size_t)gr * K + k0 + ch * 8);
        *(short8*)(&As[r][ch * 8]) = v;
      }
    }
    for (int i = tid; i < BN * CPR; i += nth) {
      int r = i / CPR, ch = i % CPR;
      short8 v = {};
      if (n0 + r < N) v = *(const short8*)(Bt + (size_t)(n0 + r) * K + k0 + ch * 8);
      *(short8*)(&Bs[r][ch * 8]) = v;
    }
    __syncthreads();
#pragma unroll
    for (int ks = 0; ks < BK; ks += 32) {
      short8 af[4], bfr[4];
#pragma unroll
      for (int mi = 0; mi < 4; ++mi)
        af[mi] = *(const short8*)(&As[wm * 64 + mi * 16 + l16][ks + quad * 8]);
#pragma unroll
      for (int ni = 0; ni < 4; ++ni)
        bfr[ni] = *(const short8*)(&Bs[wn * 64 + ni * 16 + l16][ks + quad * 8]);
#pragma unroll
      for (int mi = 0; mi < 4; ++mi)
#pragma unroll
        for (int ni = 0; ni < 4; ++ni)
          acc[mi][ni] = __builtin_amdgcn_mfma_f32_16x16x32_bf16(af[mi], bfr[ni],
                                                                acc[mi][ni], 0, 0, 0);
    }
    __syncthreads();
  }
  // C/D layout: row = quad*4 + r, col = lane&15
#pragma unroll
  for (int mi = 0; mi < 4; ++mi) {
#pragma unroll
    for (int r = 0; r < 4; ++r) {
      int grow = m0 + wm * 64 + mi * 16 + quad * 4 + r;
      if (grow >= M) continue;
#pragma unroll
      for (int ni = 0; ni < 4; ++ni) {
        int gcol = n0 + wn * 64 + ni * 16 + l16;
        C[(size_t)grow * N + gcol] = f2bu(acc[mi][ni][r] + biasc[gcol]);
      }
    }
  }
}

// ================= CSR build (counting sort by dst) =================
__global__ void hist_k(const int* __restrict__ dst, int* __restrict__ deg, int e) {
  int i = blockIdx.x * blockDim.x + threadIdx.x;
  if (i < e) atomicAdd(&deg[dst[i]], 1);
}

__global__ void scan_block_k(const int* __restrict__ deg, int* __restrict__ row_ptr,
                             int* __restrict__ bsum, int n) {
  __shared__ int s[1024];
  int i = blockIdx.x * 1024 + threadIdx.x;
  int v = (i < n) ? deg[i] : 0;
  s[threadIdx.x] = v;
  __syncthreads();
  for (int off = 1; off < 1024; off <<= 1) {
    int t = (threadIdx.x >= off) ? s[threadIdx.x - off] : 0;
    __syncthreads();
    s[threadIdx.x] += t;
    __syncthreads();
  }
  if (i < n) row_ptr[i + 1] = s[threadIdx.x];
  if (threadIdx.x == 1023) bsum[blockIdx.x] = s[1023];
}

__global__ void scan_bsum_k(int* __restrict__ bsum, int nb) {
  __shared__ int s[128];
  int v = (threadIdx.x < nb) ? bsum[threadIdx.x] : 0;
  s[threadIdx.x] = v;
  __syncthreads();
  for (int off = 1; off < 128; off <<= 1) {
    int t = (threadIdx.x >= off) ? s[threadIdx.x - off] : 0;
    __syncthreads();
    s[threadIdx.x] += t;
    __syncthreads();
  }
  if (threadIdx.x < nb) bsum[threadIdx.x] = s[threadIdx.x] - v;  // exclusive
}

// fused: finalize row_ptr AND write cursor (race-free: thread i writes
// row_ptr[i+1] and cursor[i+1] with the same value it computed locally)
__global__ void add_off_k(int* __restrict__ row_ptr, int* __restrict__ cursor,
                          const int* __restrict__ bsum, int n) {
  int i = blockIdx.x * blockDim.x + threadIdx.x;
  if (i == 0) { row_ptr[0] = 0; cursor[0] = 0; }
  if (i < n) {
    int v = row_ptr[i + 1] + bsum[i >> 10];
    row_ptr[i + 1] = v;
    if (i + 1 < n) cursor[i + 1] = v;
  }
}

__global__ void fill_k(const int* __restrict__ src, const int* __restrict__ dst,
                       const float* __restrict__ eattr, int* __restrict__ cursor,
                       int2* __restrict__ csr, int e) {
  int i = blockIdx.x * blockDim.x + threadIdx.x;
  if (i >= e) return;
  int p = atomicAdd(&cursor[dst[i]], 1);
  csr[p] = make_int2(src[i], __float_as_int(eattr[i]));
}

// ========== fused GATv2 layer 1: one wave per node, 4 ch/lane ==========
// C1 row: [xl(256) | xr(256)] bf16. lane L owns channels 4L..4L+3; head(4L)=L>>4.
// Edge loop: MASKED x4 batches (no scalar remainder) -> 4 gathers always in
// flight; out-of-range slots clamp to a valid edge and contribute exp()=0.
__global__ void gat1_k(const int* __restrict__ row_ptr, const int2* __restrict__ csr,
                       const ushort_t* __restrict__ C1,
                       const float* __restrict__ We, const float* __restrict__ att,
                       const float* __restrict__ bias, ushort_t* __restrict__ h1, int n) {
  int node = (int)(((size_t)blockIdx.x * blockDim.x + threadIdx.x) >> 6);
  int lane = threadIdx.x & 63;
  if (node >= n) return;
  int cb = lane * 4;
  ushort4v xr4 = *(const ushort4v*)(C1 + (size_t)node * 512 + 256 + cb);
  float xrr[4], Wev[4], attv[4], acc[4] = {0.f, 0.f, 0.f, 0.f};
  float esum = 0.f;
#pragma unroll
  for (int j = 0; j < 4; ++j) {
    xrr[j] = bu2f(xr4[j]);
    Wev[j] = We[cb + j];
    attv[j] = att[cb + j];
  }
  int p = row_ptr[node], p1 = row_ptr[node + 1];
  int pl = p1 - 1;
  for (int pb = p; pb < p1; pb += 4) {
    int2 ee[4];
#pragma unroll
    for (int u = 0; u < 4; ++u) {
      int q = pb + u;
      ee[u] = csr[q < p1 ? q : pl];
    }
    ushort4v xl4[4];
#pragma unroll
    for (int u = 0; u < 4; ++u)
      xl4[u] = *(const ushort4v*)(C1 + (size_t)ee[u].x * 512 + cb);
    float xv[4][4], v[4];
#pragma unroll
    for (int u = 0; u < 4; ++u) {
      float wgt = __int_as_float(ee[u].y);
      v[u] = 0.f;
#pragma unroll
      for (int j = 0; j < 4; ++j) {
        xv[u][j] = bu2f(xl4[u][j]);
        float m = xv[u][j] + xrr[j] + wgt * Wev[j];
        m = fmaxf(m, NEG * m);          // leaky_relu, slope<1: max(m, NEG*m)
        v[u] += m * attv[j];
      }
    }
#pragma unroll
    for (int u = 0; u < 4; ++u) {
      v[u] += __shfl_xor(v[u], 1, 64);
      v[u] += __shfl_xor(v[u], 2, 64);
      v[u] += __shfl_xor(v[u], 4, 64);
      v[u] += __shfl_xor(v[u], 8, 64);
    }
#pragma unroll
    for (int u = 0; u < 4; ++u) {
      float eh = (pb + u < p1) ? __expf(v[u]) : 0.f;   // mask invalid slots
      esum += eh;
#pragma unroll
      for (int j = 0; j < 4; ++j) acc[j] += eh * xv[u][j];
    }
  }
  float inv = 1.f / (esum + 1e-16f);
  ushort4v o;
#pragma unroll
  for (int j = 0; j < 4; ++j) {
    float t = acc[j] * inv + bias[cb + j];
    o[j] = f2bu(t > 0.f ? t : 0.f);   // fused relu
  }
  *(ushort4v*)(h1 + (size_t)node * D1 + cb) = o;
}

// ========== fused GATv2 layer 2: one wave per node, 8 parallel edge slots ==========
// 8-lane group g owns edge slot g (4 ch/lane x 8 lanes = 32 channels).
// Masked batch of 8 edges -> typically ONE iteration per node (Poisson(5) degrees),
// 8 gathers in flight, then a 3-step cross-group reduce.
__global__ void gat2_k(const int* __restrict__ row_ptr, const int2* __restrict__ csr,
                       const ushort_t* __restrict__ C2,
                       const float* __restrict__ We, const float* __restrict__ att,
                       const float* __restrict__ bias, float* __restrict__ out, int n) {
  int node = (int)(((size_t)blockIdx.x * blockDim.x + threadIdx.x) >> 6);
  int lane = threadIdx.x & 63;
  if (node >= n) return;
  int g = lane >> 3;          // edge slot 0..7
  int cb = (lane & 7) * 4;    // channel base 0..28
  ushort4v xr4 = *(const ushort4v*)(C2 + (size_t)node * 64 + 32 + cb);
  float xrr[4], Wev[4], attv[4], acc[4] = {0.f, 0.f, 0.f, 0.f};
  float esum = 0.f;
#pragma unroll
  for (int j = 0; j < 4; ++j) {
    xrr[j] = bu2f(xr4[j]);
    Wev[j] = We[cb + j];
    attv[j] = att[cb + j];
  }
  int p = row_ptr[node], p1 = row_ptr[node + 1];
  int pl = p1 - 1;
  for (int pb = p; pb < p1; pb += 8) {
    int q = pb + g;
    int2 ed = csr[q < p1 ? q : pl];
    float wgt = __int_as_float(ed.y);
    ushort4v xl4 = *(const ushort4v*)(C2 + (size_t)ed.x * 64 + cb);
    float xv[4], v = 0.f;
#pragma unroll
    for (int j = 0; j < 4; ++j) {
      xv[j] = bu2f(xl4[j]);
      float m = xv[j] + xrr[j] + wgt * Wev[j];
      m = fmaxf(m, NEG * m);
      v += m * attv[j];
    }
    v += __shfl_xor(v, 1, 64);
    v += __shfl_xor(v, 2, 64);
    v += __shfl_xor(v, 4, 64);
    float eh = (q < p1) ? __expf(v) : 0.f;
    esum += eh;
#pragma unroll
    for (int j = 0; j < 4; ++j) acc[j] += eh * xv[j];
  }
  // reduce across the 8 edge-slot groups
  esum += __shfl_xor(esum, 8, 64);
  esum += __shfl_xor(esum, 16, 64);
  esum += __shfl_xor(esum, 32, 64);
#pragma unroll
  for (int j = 0; j < 4; ++j) {
    acc[j] += __shfl_xor(acc[j], 8, 64);
    acc[j] += __shfl_xor(acc[j], 16, 64);
    acc[j] += __shfl_xor(acc[j], 32, 64);
  }
  if (lane < 8) {
    float inv = 1.f / (esum + 1e-16f);
    f32x4 ov;
#pragma unroll
    for (int j = 0; j < 4; ++j) ov[j] = acc[j] * inv + bias[cb + j];
    *(f32x4*)(out + (size_t)node * OUT_C + cb) = ov;
  }
}

extern "C" void kernel_launch(void* const* d_in, const int* in_sizes, int n_in,
                              void* d_out, int out_size, void* d_ws, size_t ws_size,
                              hipStream_t stream) {
  const float* x     = (const float*)d_in[0];
  const int*   eidx  = (const int*)d_in[1];
  const float* eattr = (const float*)d_in[2];
  const float* Wl1 = (const float*)d_in[3];
  const float* bl1 = (const float*)d_in[4];
  const float* Wr1 = (const float*)d_in[5];
  const float* br1 = (const float*)d_in[6];
  const float* We1 = (const float*)d_in[7];
  const float* att1 = (const float*)d_in[8];
  const float* b1  = (const float*)d_in[9];
  const float* Wl2 = (const float*)d_in[10];
  const float* bl2 = (const float*)d_in[11];
  const float* Wr2 = (const float*)d_in[12];
  const float* br2 = (const float*)d_in[13];
  const float* We2 = (const float*)d_in[14];
  const float* att2 = (const float*)d_in[15];
  const float* b2  = (const float*)d_in[16];

  const int n = in_sizes[0] / F_IN;   // 100000
  const int e = in_sizes[2];          // 500000
  const int* src = eidx;
  const int* dst = eidx + e;
  float* out = (float*)d_out;

  // ---- workspace (~171 MB) ----
  char* w = (char*)d_ws;
  ushort_t* C1   = (ushort_t*)w;  w += (size_t)n * 512 * 2;      // 102.4 MB
  ushort_t* h1b  = (ushort_t*)w;  w += (size_t)n * D1 * 2;       // 51.2 MB
  ushort_t* C2   = (ushort_t*)w;  w += (size_t)n * 64 * 2;       // 12.8 MB
  ushort_t* Bt1  = (ushort_t*)w;  w += 512 * F_IN * 2;
  ushort_t* Bt2  = (ushort_t*)w;  w += 64 * D1 * 2;
  float* bias1c  = (float*)w;     w += 512 * 4;
  float* bias2c  = (float*)w;     w += 64 * 4;
  int2*  csr     = (int2*)w;      w += (size_t)e * 8;
  int*   row_ptr = (int*)w;       w += ((size_t)n + 1) * 4;
  int*   cursor  = (int*)w;       w += (size_t)n * 4;
  int*   bsum    = (int*)w;       w += 512;
  int*   deg = cursor;            // disjoint lifetimes

  dim3 blk(256);
  const int nb = (n + 1023) / 1024;   // 98 <= 128

  // ---- prep: transpose+convert weights (both layers, one launch) ----
  prep_k<<<320, blk, 0, stream>>>(Wl1, Wr1, bl1, br1, Bt1, bias1c,
                                  Wl2, Wr2, bl2, br2, Bt2, bias2c);

  // ---- CSR build ----
  hipMemsetAsync(deg, 0, (size_t)n * sizeof(int), stream);
  hist_k<<<(e + 255) / 256, blk, 0, stream>>>(dst, deg, e);
  scan_block_k<<<nb, 1024, 0, stream>>>(deg, row_ptr, bsum, n);
  scan_bsum_k<<<1, 128, 0, stream>>>(bsum, nb);
  add_off_k<<<(n + 255) / 256, blk, 0, stream>>>(row_ptr, cursor, bsum, n);
  fill_k<<<(e + 255) / 256, blk, 0, stream>>>(src, dst, eattr, cursor, csr, e);

  // ---- layer 1: C1 = x @ [Wl1|Wr1] + bias  (n x 128 @ 128 x 512) ----
  gemm1_k<<<(n + 127) / 128, blk, 0, stream>>>(x, Bt1, bias1c, C1, n);
  gat1_k<<<(n + 3) / 4, blk, 0, stream>>>(row_ptr, csr, C1, We1, att1, b1, h1b, n);

  // ---- layer 2: C2 = h1 @ [Wl2|Wr2] + bias  (n x 256 @ 256 x 64) ----
  mfma_gemm<2, 1, 64, false><<<dim3(1, (n + 127) / 128), dim3(128), 0, stream>>>(
      h1b, Bt2, bias2c, C2, n, 64, D1);
  gat2_k<<<(n + 3) / 4, blk, 0, stream>>>(row_ptr, csr, C2, We2, att2, b2, out, n);
}

// Round 3
// 363.936 us; speedup vs baseline: 1.0841x; 1.0841x over previous
//
#include <hip/hip_runtime.h>
#include <cstddef>
#include <cstdint>

#define F_IN 128
#define D1   256   // HEADS*HID
#define HEADS 4
#define HID   64
#define OUT_C 32
#define NEG   0.2f

typedef unsigned short ushort_t;
typedef __attribute__((ext_vector_type(8))) short short8;
typedef __attribute__((ext_vector_type(4))) float f32x4;
typedef __attribute__((ext_vector_type(4))) unsigned short ushort4v;

__device__ __forceinline__ float bu2f(ushort_t u) {
  return __uint_as_float(((unsigned)u) << 16);
}
__device__ __forceinline__ ushort_t f2bu(float f) {
  unsigned u = __float_as_uint(f);
  return (ushort_t)((u + 0x7FFF + ((u >> 16) & 1)) >> 16);   // RNE
}

// ---- weight prep (fused): Bt[nn][k] = concat(Wl,Wr)^T in bf16, both layers ----
__global__ void prep_k(const float* __restrict__ Wl1, const float* __restrict__ Wr1,
                       const float* __restrict__ bl1, const float* __restrict__ br1,
                       ushort_t* __restrict__ Bt1, float* __restrict__ bias1c,
                       const float* __restrict__ Wl2, const float* __restrict__ Wr2,
                       const float* __restrict__ bl2, const float* __restrict__ br2,
                       ushort_t* __restrict__ Bt2, float* __restrict__ bias2c) {
  int b = blockIdx.x;
  if (b < 256) {           // layer 1: 512 x 128
    int i = b * 256 + threadIdx.x;
    int nn = i >> 7, k = i & 127;
    float v = (nn < D1) ? Wl1[(size_t)k * D1 + nn] : Wr1[(size_t)k * D1 + (nn - D1)];
    Bt1[(size_t)nn * F_IN + k] = f2bu(v);
    if (k == 0) bias1c[nn] = (nn < D1) ? bl1[nn] : br1[nn - D1];
  } else {                 // layer 2: 64 x 256
    int i = (b - 256) * 256 + threadIdx.x;
    int nn = i >> 8, k = i & 255;
    float v = (nn < OUT_C) ? Wl2[(size_t)k * OUT_C + nn] : Wr2[(size_t)k * OUT_C + (nn - OUT_C)];
    Bt2[(size_t)nn * D1 + k] = f2bu(v);
    if (k == 0) bias2c[nn] = (nn < OUT_C) ? bl2[nn] : br2[nn - OUT_C];
  }
}

// ---- bf16 MFMA GEMM (NT): C[M,N] = bf16(A[M,K] @ Bt[N,K]^T + biasc) ----
// CVT=true: A is fp32, converted to bf16 in-register during LDS staging.
// Round-0 structure (LDS-staged A AND B, M-major) restored.
// SWZ=true (gemm1 only, 4 N-panels): flat 1D grid decoded as
//   wgid = m_l + 8*(panel + 4*m_h),  mtile = m_h*8 + m_l
// so xcd = wgid%8 = mtile%8 -> all 4 panel-blocks sharing an A-tile run on the
// SAME XCD, 8 wgids apart (near-simultaneous) -> A re-reads hit that XCD's L2
// instead of bouncing through L3/HBM across incoherent L2s.
template <int WM, int WN, int BK, bool CVT, bool SWZ>
__global__ void mfma_gemm(const void* __restrict__ Av, const ushort_t* __restrict__ Bt,
                          const float* __restrict__ biasc, ushort_t* __restrict__ C,
                          int M, int N, int K) {
  constexpr int BM = WM * 64, BN = WN * 64;
  constexpr int LD = BK + 8;
  constexpr int CPR = BK / 8;           // 8-elem chunks per row
  __shared__ ushort_t As[BM][LD];
  __shared__ ushort_t Bs[BN][LD];
  const int tid = threadIdx.x;
  const int wave = tid >> 6, lane = tid & 63;
  const int wm = wave % WM, wn = wave / WM;
  const int quad = lane >> 4, l16 = lane & 15;
  int m0, n0;
  if (SWZ) {                            // requires N == 4*BN
    int wgid = blockIdx.x;
    int m_l = wgid & 7;
    int rest = wgid >> 3;
    int panel = rest & 3, m_h = rest >> 2;
    int mtile = m_h * 8 + m_l;
    if (mtile * BM >= M) return;        // uniform across block
    m0 = mtile * BM;
    n0 = panel * BN;
  } else {
    m0 = blockIdx.x * BM;
    n0 = blockIdx.y * BN;
  }
  const int nth = WM * WN * 64;
  f32x4 acc[4][4] = {};
  for (int k0 = 0; k0 < K; k0 += BK) {
    for (int i = tid; i < BM * CPR; i += nth) {
      int r = i / CPR, ch = i % CPR;
      int gr = m0 + r;
      if (CVT) {
        const float* A32 = (const float*)Av;
        f32x4 v0 = {}, v1 = {};
        if (gr < M) {
          const float* p = A32 + (size_t)gr * K + k0 + ch * 8;
          v0 = *(const f32x4*)p;
          v1 = *(const f32x4*)(p + 4);
        }
        short8 o;
        o[0] = (short)f2bu(v0[0]); o[1] = (short)f2bu(v0[1]);
        o[2] = (short)f2bu(v0[2]); o[3] = (short)f2bu(v0[3]);
        o[4] = (short)f2bu(v1[0]); o[5] = (short)f2bu(v1[1]);
        o[6] = (short)f2bu(v1[2]); o[7] = (short)f2bu(v1[3]);
        *(short8*)(&As[r][ch * 8]) = o;
      } else {
        const ushort_t* A16 = (const ushort_t*)Av;
        short8 v = {};
        if (gr < M) v = *(const short8*)(A16 + (size_t)gr * K + k0 + ch * 8);
        *(short8*)(&As[r][ch * 8]) = v;
      }
    }
    for (int i = tid; i < BN * CPR; i += nth) {
      int r = i / CPR, ch = i % CPR;
      short8 v = {};
      if (n0 + r < N) v = *(const short8*)(Bt + (size_t)(n0 + r) * K + k0 + ch * 8);
      *(short8*)(&Bs[r][ch * 8]) = v;
    }
    __syncthreads();
#pragma unroll
    for (int ks = 0; ks < BK; ks += 32) {
      short8 af[4], bfr[4];
#pragma unroll
      for (int mi = 0; mi < 4; ++mi)
        af[mi] = *(const short8*)(&As[wm * 64 + mi * 16 + l16][ks + quad * 8]);
#pragma unroll
      for (int ni = 0; ni < 4; ++ni)
        bfr[ni] = *(const short8*)(&Bs[wn * 64 + ni * 16 + l16][ks + quad * 8]);
#pragma unroll
      for (int mi = 0; mi < 4; ++mi)
#pragma unroll
        for (int ni = 0; ni < 4; ++ni)
          acc[mi][ni] = __builtin_amdgcn_mfma_f32_16x16x32_bf16(af[mi], bfr[ni],
                                                                acc[mi][ni], 0, 0, 0);
    }
    __syncthreads();
  }
  // C/D layout: row = quad*4 + r, col = lane&15
#pragma unroll
  for (int mi = 0; mi < 4; ++mi) {
#pragma unroll
    for (int r = 0; r < 4; ++r) {
      int grow = m0 + wm * 64 + mi * 16 + quad * 4 + r;
      if (grow >= M) continue;
#pragma unroll
      for (int ni = 0; ni < 4; ++ni) {
        int gcol = n0 + wn * 64 + ni * 16 + l16;
        C[(size_t)grow * N + gcol] = f2bu(acc[mi][ni][r] + biasc[gcol]);
      }
    }
  }
}

// ================= CSR build (counting sort by dst) =================
__global__ void hist_k(const int* __restrict__ dst, int* __restrict__ deg, int e) {
  int i = blockIdx.x * blockDim.x + threadIdx.x;
  if (i < e) atomicAdd(&deg[dst[i]], 1);
}

__global__ void scan_block_k(const int* __restrict__ deg, int* __restrict__ row_ptr,
                             int* __restrict__ bsum, int n) {
  __shared__ int s[1024];
  int i = blockIdx.x * 1024 + threadIdx.x;
  int v = (i < n) ? deg[i] : 0;
  s[threadIdx.x] = v;
  __syncthreads();
  for (int off = 1; off < 1024; off <<= 1) {
    int t = (threadIdx.x >= off) ? s[threadIdx.x - off] : 0;
    __syncthreads();
    s[threadIdx.x] += t;
    __syncthreads();
  }
  if (i < n) row_ptr[i + 1] = s[threadIdx.x];
  if (threadIdx.x == 1023) bsum[blockIdx.x] = s[1023];
}

__global__ void scan_bsum_k(int* __restrict__ bsum, int nb) {
  __shared__ int s[128];
  int v = (threadIdx.x < nb) ? bsum[threadIdx.x] : 0;
  s[threadIdx.x] = v;
  __syncthreads();
  for (int off = 1; off < 128; off <<= 1) {
    int t = (threadIdx.x >= off) ? s[threadIdx.x - off] : 0;
    __syncthreads();
    s[threadIdx.x] += t;
    __syncthreads();
  }
  if (threadIdx.x < nb) bsum[threadIdx.x] = s[threadIdx.x] - v;  // exclusive
}

// fused: finalize row_ptr AND write cursor (race-free: thread i writes
// row_ptr[i+1] and cursor[i+1] with the same value it computed locally)
__global__ void add_off_k(int* __restrict__ row_ptr, int* __restrict__ cursor,
                          const int* __restrict__ bsum, int n) {
  int i = blockIdx.x * blockDim.x + threadIdx.x;
  if (i == 0) { row_ptr[0] = 0; cursor[0] = 0; }
  if (i < n) {
    int v = row_ptr[i + 1] + bsum[i >> 10];
    row_ptr[i + 1] = v;
    if (i + 1 < n) cursor[i + 1] = v;
  }
}

__global__ void fill_k(const int* __restrict__ src, const int* __restrict__ dst,
                       const float* __restrict__ eattr, int* __restrict__ cursor,
                       int2* __restrict__ csr, int e) {
  int i = blockIdx.x * blockDim.x + threadIdx.x;
  if (i >= e) return;
  int p = atomicAdd(&cursor[dst[i]], 1);
  csr[p] = make_int2(src[i], __float_as_int(eattr[i]));
}

// ========== fused GATv2 layer 1: one wave per node, 4 ch/lane ==========
// C1 row: [xl(256) | xr(256)] bf16. lane L owns channels 4L..4L+3; head(4L)=L>>4.
// Edge loop: MASKED x4 batches (no scalar remainder) -> 4 gathers always in
// flight; out-of-range slots clamp to a valid edge and contribute exp()=0.
__global__ void gat1_k(const int* __restrict__ row_ptr, const int2* __restrict__ csr,
                       const ushort_t* __restrict__ C1,
                       const float* __restrict__ We, const float* __restrict__ att,
                       const float* __restrict__ bias, ushort_t* __restrict__ h1, int n) {
  int node = (int)(((size_t)blockIdx.x * blockDim.x + threadIdx.x) >> 6);
  int lane = threadIdx.x & 63;
  if (node >= n) return;
  int cb = lane * 4;
  ushort4v xr4 = *(const ushort4v*)(C1 + (size_t)node * 512 + 256 + cb);
  float xrr[4], Wev[4], attv[4], acc[4] = {0.f, 0.f, 0.f, 0.f};
  float esum = 0.f;
#pragma unroll
  for (int j = 0; j < 4; ++j) {
    xrr[j] = bu2f(xr4[j]);
    Wev[j] = We[cb + j];
    attv[j] = att[cb + j];
  }
  int p = row_ptr[node], p1 = row_ptr[node + 1];
  int pl = p1 - 1;
  for (int pb = p; pb < p1; pb += 4) {
    int2 ee[4];
#pragma unroll
    for (int u = 0; u < 4; ++u) {
      int q = pb + u;
      ee[u] = csr[q < p1 ? q : pl];
    }
    ushort4v xl4[4];
#pragma unroll
    for (int u = 0; u < 4; ++u)
      xl4[u] = *(const ushort4v*)(C1 + (size_t)ee[u].x * 512 + cb);
    float xv[4][4], v[4];
#pragma unroll
    for (int u = 0; u < 4; ++u) {
      float wgt = __int_as_float(ee[u].y);
      v[u] = 0.f;
#pragma unroll
      for (int j = 0; j < 4; ++j) {
        xv[u][j] = bu2f(xl4[u][j]);
        float m = xv[u][j] + xrr[j] + wgt * Wev[j];
        m = fmaxf(m, NEG * m);          // leaky_relu, slope<1: max(m, NEG*m)
        v[u] += m * attv[j];
      }
    }
#pragma unroll
    for (int u = 0; u < 4; ++u) {
      v[u] += __shfl_xor(v[u], 1, 64);
      v[u] += __shfl_xor(v[u], 2, 64);
      v[u] += __shfl_xor(v[u], 4, 64);
      v[u] += __shfl_xor(v[u], 8, 64);
    }
#pragma unroll
    for (int u = 0; u < 4; ++u) {
      float eh = (pb + u < p1) ? __expf(v[u]) : 0.f;   // mask invalid slots
      esum += eh;
#pragma unroll
      for (int j = 0; j < 4; ++j) acc[j] += eh * xv[u][j];
    }
  }
  float inv = 1.f / (esum + 1e-16f);
  ushort4v o;
#pragma unroll
  for (int j = 0; j < 4; ++j) {
    float t = acc[j] * inv + bias[cb + j];
    o[j] = f2bu(t > 0.f ? t : 0.f);   // fused relu
  }
  *(ushort4v*)(h1 + (size_t)node * D1 + cb) = o;
}

// ========== fused GATv2 layer 2: one wave per node, 8 parallel edge slots ==========
// 8-lane group g owns edge slot g (4 ch/lane x 8 lanes = 32 channels).
// Masked batch of 8 edges -> typically ONE iteration per node (Poisson(5) degrees),
// 8 gathers in flight, then a 3-step cross-group reduce.
__global__ void gat2_k(const int* __restrict__ row_ptr, const int2* __restrict__ csr,
                       const ushort_t* __restrict__ C2,
                       const float* __restrict__ We, const float* __restrict__ att,
                       const float* __restrict__ bias, float* __restrict__ out, int n) {
  int node = (int)(((size_t)blockIdx.x * blockDim.x + threadIdx.x) >> 6);
  int lane = threadIdx.x & 63;
  if (node >= n) return;
  int g = lane >> 3;          // edge slot 0..7
  int cb = (lane & 7) * 4;    // channel base 0..28
  ushort4v xr4 = *(const ushort4v*)(C2 + (size_t)node * 64 + 32 + cb);
  float xrr[4], Wev[4], attv[4], acc[4] = {0.f, 0.f, 0.f, 0.f};
  float esum = 0.f;
#pragma unroll
  for (int j = 0; j < 4; ++j) {
    xrr[j] = bu2f(xr4[j]);
    Wev[j] = We[cb + j];
    attv[j] = att[cb + j];
  }
  int p = row_ptr[node], p1 = row_ptr[node + 1];
  int pl = p1 - 1;
  for (int pb = p; pb < p1; pb += 8) {
    int q = pb + g;
    int2 ed = csr[q < p1 ? q : pl];
    float wgt = __int_as_float(ed.y);
    ushort4v xl4 = *(const ushort4v*)(C2 + (size_t)ed.x * 64 + cb);
    float xv[4], v = 0.f;
#pragma unroll
    for (int j = 0; j < 4; ++j) {
      xv[j] = bu2f(xl4[j]);
      float m = xv[j] + xrr[j] + wgt * Wev[j];
      m = fmaxf(m, NEG * m);
      v += m * attv[j];
    }
    v += __shfl_xor(v, 1, 64);
    v += __shfl_xor(v, 2, 64);
    v += __shfl_xor(v, 4, 64);
    float eh = (q < p1) ? __expf(v) : 0.f;
    esum += eh;
#pragma unroll
    for (int j = 0; j < 4; ++j) acc[j] += eh * xv[j];
  }
  // reduce across the 8 edge-slot groups
  esum += __shfl_xor(esum, 8, 64);
  esum += __shfl_xor(esum, 16, 64);
  esum += __shfl_xor(esum, 32, 64);
#pragma unroll
  for (int j = 0; j < 4; ++j) {
    acc[j] += __shfl_xor(acc[j], 8, 64);
    acc[j] += __shfl_xor(acc[j], 16, 64);
    acc[j] += __shfl_xor(acc[j], 32, 64);
  }
  if (lane < 8) {
    float inv = 1.f / (esum + 1e-16f);
    f32x4 ov;
#pragma unroll
    for (int j = 0; j < 4; ++j) ov[j] = acc[j] * inv + bias[cb + j];
    *(f32x4*)(out + (size_t)node * OUT_C + cb) = ov;
  }
}

extern "C" void kernel_launch(void* const* d_in, const int* in_sizes, int n_in,
                              void* d_out, int out_size, void* d_ws, size_t ws_size,
                              hipStream_t stream) {
  const float* x     = (const float*)d_in[0];
  const int*   eidx  = (const int*)d_in[1];
  const float* eattr = (const float*)d_in[2];
  const float* Wl1 = (const float*)d_in[3];
  const float* bl1 = (const float*)d_in[4];
  const float* Wr1 = (const float*)d_in[5];
  const float* br1 = (const float*)d_in[6];
  const float* We1 = (const float*)d_in[7];
  const float* att1 = (const float*)d_in[8];
  const float* b1  = (const float*)d_in[9];
  const float* Wl2 = (const float*)d_in[10];
  const float* bl2 = (const float*)d_in[11];
  const float* Wr2 = (const float*)d_in[12];
  const float* br2 = (const float*)d_in[13];
  const float* We2 = (const float*)d_in[14];
  const float* att2 = (const float*)d_in[15];
  const float* b2  = (const float*)d_in[16];

  const int n = in_sizes[0] / F_IN;   // 100000
  const int e = in_sizes[2];          // 500000
  const int* src = eidx;
  const int* dst = eidx + e;
  float* out = (float*)d_out;

  // ---- workspace (~171 MB) ----
  char* w = (char*)d_ws;
  ushort_t* C1   = (ushort_t*)w;  w += (size_t)n * 512 * 2;      // 102.4 MB
  ushort_t* h1b  = (ushort_t*)w;  w += (size_t)n * D1 * 2;       // 51.2 MB
  ushort_t* C2   = (ushort_t*)w;  w += (size_t)n * 64 * 2;       // 12.8 MB
  ushort_t* Bt1  = (ushort_t*)w;  w += 512 * F_IN * 2;
  ushort_t* Bt2  = (ushort_t*)w;  w += 64 * D1 * 2;
  float* bias1c  = (float*)w;     w += 512 * 4;
  float* bias2c  = (float*)w;     w += 64 * 4;
  int2*  csr     = (int2*)w;      w += (size_t)e * 8;
  int*   row_ptr = (int*)w;       w += ((size_t)n + 1) * 4;
  int*   cursor  = (int*)w;       w += (size_t)n * 4;
  int*   bsum    = (int*)w;       w += 512;
  int*   deg = cursor;            // disjoint lifetimes

  dim3 blk(256);
  const int nb = (n + 1023) / 1024;   // 98 <= 128
  const int nmt = (n + 127) / 128;    // 782 M-tiles

  // ---- prep: transpose+convert weights (both layers, one launch) ----
  prep_k<<<320, blk, 0, stream>>>(Wl1, Wr1, bl1, br1, Bt1, bias1c,
                                  Wl2, Wr2, bl2, br2, Bt2, bias2c);

  // ---- CSR build ----
  hipMemsetAsync(deg, 0, (size_t)n * sizeof(int), stream);
  hist_k<<<(e + 255) / 256, blk, 0, stream>>>(dst, deg, e);
  scan_block_k<<<nb, 1024, 0, stream>>>(deg, row_ptr, bsum, n);
  scan_bsum_k<<<1, 128, 0, stream>>>(bsum, nb);
  add_off_k<<<(n + 255) / 256, blk, 0, stream>>>(row_ptr, cursor, bsum, n);
  fill_k<<<(e + 255) / 256, blk, 0, stream>>>(src, dst, eattr, cursor, csr, e);

  // ---- layer 1: C1 = x @ [Wl1|Wr1] + bias  (n x 128 @ 128 x 512, CVT fp32) ----
  // XCD-swizzled flat grid: ceil(nmt/8)*8 mtiles * 4 panels
  const int g1blocks = ((nmt + 7) / 8) * 8 * 4;
  mfma_gemm<2, 2, 64, true, true><<<g1blocks, blk, 0, stream>>>(
      x, Bt1, bias1c, C1, n, 512, F_IN);
  gat1_k<<<(n + 3) / 4, blk, 0, stream>>>(row_ptr, csr, C1, We1, att1, b1, h1b, n);

  // ---- layer 2: C2 = h1 @ [Wl2|Wr2] + bias  (n x 256 @ 256 x 64) ----
  mfma_gemm<2, 1, 64, false, false><<<dim3(nmt, 1), dim3(128), 0, stream>>>(
      h1b, Bt2, bias2c, C2, n, 64, D1);
  gat2_k<<<(n + 3) / 4, blk, 0, stream>>>(row_ptr, csr, C2, We2, att2, b2, out, n);
}

// Round 4
// 353.591 us; speedup vs baseline: 1.1158x; 1.0293x over previous
//
#include <hip/hip_runtime.h>
#include <cstddef>
#include <cstdint>

#define F_IN 128
#define D1   256   // HEADS*HID
#define HEADS 4
#define HID   64
#define OUT_C 32
#define NEG   0.2f

typedef unsigned short ushort_t;
typedef __attribute__((ext_vector_type(8))) short short8;
typedef __attribute__((ext_vector_type(4))) float f32x4;
typedef __attribute__((ext_vector_type(4))) unsigned short ushort4v;

__device__ __forceinline__ float bu2f(ushort_t u) {
  return __uint_as_float(((unsigned)u) << 16);
}
__device__ __forceinline__ ushort_t f2bu(float f) {
  unsigned u = __float_as_uint(f);
  return (ushort_t)((u + 0x7FFF + ((u >> 16) & 1)) >> 16);   // RNE
}

// ---- weight prep (fused): Bt[nn][k] = concat(Wl,Wr)^T in bf16, both layers ----
__global__ void prep_k(const float* __restrict__ Wl1, const float* __restrict__ Wr1,
                       const float* __restrict__ bl1, const float* __restrict__ br1,
                       ushort_t* __restrict__ Bt1, float* __restrict__ bias1c,
                       const float* __restrict__ Wl2, const float* __restrict__ Wr2,
                       const float* __restrict__ bl2, const float* __restrict__ br2,
                       ushort_t* __restrict__ Bt2, float* __restrict__ bias2c) {
  int b = blockIdx.x;
  if (b < 256) {           // layer 1: 512 x 128
    int i = b * 256 + threadIdx.x;
    int nn = i >> 7, k = i & 127;
    float v = (nn < D1) ? Wl1[(size_t)k * D1 + nn] : Wr1[(size_t)k * D1 + (nn - D1)];
    Bt1[(size_t)nn * F_IN + k] = f2bu(v);
    if (k == 0) bias1c[nn] = (nn < D1) ? bl1[nn] : br1[nn - D1];
  } else {                 // layer 2: 64 x 256
    int i = (b - 256) * 256 + threadIdx.x;
    int nn = i >> 8, k = i & 255;
    float v = (nn < OUT_C) ? Wl2[(size_t)k * OUT_C + nn] : Wr2[(size_t)k * OUT_C + (nn - OUT_C)];
    Bt2[(size_t)nn * D1 + k] = f2bu(v);
    if (k == 0) bias2c[nn] = (nn < OUT_C) ? bl2[nn] : br2[nn - OUT_C];
  }
}

// ---- layer-1 GEMM v4: C1[M,512] = bf16(x[M,128] @ Bt1[512,128]^T + bias) ----
// One block per 128-row M-tile. A-tile (full K=128) staged in LDS ONCE ->
// x fetched from HBM exactly once (fixes the 4x A re-fetch of the panel-grid
// version). B panels staged in LDS per (panel, k-half) from the L2-resident
// 128 KB Bt1 (fixes round-2's latency-exposed B-from-global). 53.2 KB LDS ->
// 3 blocks/CU = 12 waves/CU. Strides: As 272 B (68 dw === 4 mod 32) and
// Bs 144 B (36 dw === 4 mod 32) -> max 2-way bank aliasing (free on CDNA4).
__global__ __launch_bounds__(256, 3) void gemm1_k(
    const float* __restrict__ x, const ushort_t* __restrict__ Bt,
    const float* __restrict__ biasc, ushort_t* __restrict__ C, int M) {
  constexpr int LDA = F_IN + 8;   // 136 shorts
  constexpr int LDB = 64 + 8;     // 72 shorts
  __shared__ ushort_t As[128][LDA];   // 34816 B
  __shared__ ushort_t Bs[128][LDB];   // 18432 B
  const int tid = threadIdx.x;
  const int wave = tid >> 6, lane = tid & 63;
  const int wm = wave & 1, wn = wave >> 1;     // 2x2 waves over 128x128 out
  const int quad = lane >> 4, l16 = lane & 15;
  const int m0 = blockIdx.x * 128;
  // ---- stage A (fp32 -> bf16): 128 rows x 16 chunks of 8 elems ----
#pragma unroll
  for (int it = 0; it < 8; ++it) {
    int i = it * 256 + tid;
    int r = i >> 4, ch = i & 15;
    int gr = m0 + r;
    f32x4 v0 = {}, v1 = {};
    if (gr < M) {
      const float* p = x + (size_t)gr * F_IN + ch * 8;
      v0 = *(const f32x4*)p;
      v1 = *(const f32x4*)(p + 4);
    }
    short8 o;
    o[0] = (short)f2bu(v0[0]); o[1] = (short)f2bu(v0[1]);
    o[2] = (short)f2bu(v0[2]); o[3] = (short)f2bu(v0[3]);
    o[4] = (short)f2bu(v1[0]); o[5] = (short)f2bu(v1[1]);
    o[6] = (short)f2bu(v1[2]); o[7] = (short)f2bu(v1[3]);
    *(short8*)(&As[r][ch * 8]) = o;
  }
#pragma unroll
  for (int panel = 0; panel < 4; ++panel) {
    f32x4 acc[4][4] = {};
#pragma unroll
    for (int kh = 0; kh < 2; ++kh) {
      __syncthreads();   // Bs safe to overwrite (also covers A-stage at panel0)
      // stage Bs: 128 rows x 8 chunks of 8, k-cols [kh*64, kh*64+64)
#pragma unroll
      for (int it = 0; it < 4; ++it) {
        int i = it * 256 + tid;
        int r = i >> 3, ch = i & 7;
        short8 v = *(const short8*)(Bt + (size_t)(panel * 128 + r) * F_IN + kh * 64 + ch * 8);
        *(short8*)(&Bs[r][ch * 8]) = v;
      }
      __syncthreads();
#pragma unroll
      for (int ks = 0; ks < 2; ++ks) {
        short8 af[4], bfr[4];
#pragma unroll
        for (int mi = 0; mi < 4; ++mi)
          af[mi] = *(const short8*)(&As[wm * 64 + mi * 16 + l16][kh * 64 + ks * 32 + quad * 8]);
#pragma unroll
        for (int ni = 0; ni < 4; ++ni)
          bfr[ni] = *(const short8*)(&Bs[wn * 64 + ni * 16 + l16][ks * 32 + quad * 8]);
#pragma unroll
        for (int mi = 0; mi < 4; ++mi)
#pragma unroll
          for (int ni = 0; ni < 4; ++ni)
            acc[mi][ni] = __builtin_amdgcn_mfma_f32_16x16x32_bf16(af[mi], bfr[ni],
                                                                  acc[mi][ni], 0, 0, 0);
      }
    }
    // ---- epilogue for this panel; C/D layout: row = quad*4 + r, col = l16 ----
    const int nbase = panel * 128 + wn * 64;
    float bv[4];
#pragma unroll
    for (int ni = 0; ni < 4; ++ni) bv[ni] = biasc[nbase + ni * 16 + l16];
#pragma unroll
    for (int mi = 0; mi < 4; ++mi) {
#pragma unroll
      for (int r = 0; r < 4; ++r) {
        int grow = m0 + wm * 64 + mi * 16 + quad * 4 + r;
        if (grow >= M) continue;
#pragma unroll
        for (int ni = 0; ni < 4; ++ni) {
          int gcol = nbase + ni * 16 + l16;
          C[(size_t)grow * 512 + gcol] = f2bu(acc[mi][ni][r] + bv[ni]);
        }
      }
    }
  }
}

// ---- bf16 MFMA GEMM (NT) for layer 2: C[M,N] = bf16(A[M,K] @ Bt[N,K]^T + bias) ----
template <int WM, int WN, int BK, bool CVT>
__global__ void mfma_gemm(const void* __restrict__ Av, const ushort_t* __restrict__ Bt,
                          const float* __restrict__ biasc, ushort_t* __restrict__ C,
                          int M, int N, int K) {
  constexpr int BM = WM * 64, BN = WN * 64;
  constexpr int LD = BK + 8;
  constexpr int CPR = BK / 8;           // 8-elem chunks per row
  __shared__ ushort_t As[BM][LD];
  __shared__ ushort_t Bs[BN][LD];
  const int tid = threadIdx.x;
  const int wave = tid >> 6, lane = tid & 63;
  const int wm = wave % WM, wn = wave / WM;
  const int quad = lane >> 4, l16 = lane & 15;
  const int m0 = blockIdx.x * BM, n0 = blockIdx.y * BN;
  const int nth = WM * WN * 64;
  f32x4 acc[4][4] = {};
  for (int k0 = 0; k0 < K; k0 += BK) {
    for (int i = tid; i < BM * CPR; i += nth) {
      int r = i / CPR, ch = i % CPR;
      int gr = m0 + r;
      if (CVT) {
        const float* A32 = (const float*)Av;
        f32x4 v0 = {}, v1 = {};
        if (gr < M) {
          const float* p = A32 + (size_t)gr * K + k0 + ch * 8;
          v0 = *(const f32x4*)p;
          v1 = *(const f32x4*)(p + 4);
        }
        short8 o;
        o[0] = (short)f2bu(v0[0]); o[1] = (short)f2bu(v0[1]);
        o[2] = (short)f2bu(v0[2]); o[3] = (short)f2bu(v0[3]);
        o[4] = (short)f2bu(v1[0]); o[5] = (short)f2bu(v1[1]);
        o[6] = (short)f2bu(v1[2]); o[7] = (short)f2bu(v1[3]);
        *(short8*)(&As[r][ch * 8]) = o;
      } else {
        const ushort_t* A16 = (const ushort_t*)Av;
        short8 v = {};
        if (gr < M) v = *(const short8*)(A16 + (size_t)gr * K + k0 + ch * 8);
        *(short8*)(&As[r][ch * 8]) = v;
      }
    }
    for (int i = tid; i < BN * CPR; i += nth) {
      int r = i / CPR, ch = i % CPR;
      short8 v = {};
      if (n0 + r < N) v = *(const short8*)(Bt + (size_t)(n0 + r) * K + k0 + ch * 8);
      *(short8*)(&Bs[r][ch * 8]) = v;
    }
    __syncthreads();
#pragma unroll
    for (int ks = 0; ks < BK; ks += 32) {
      short8 af[4], bfr[4];
#pragma unroll
      for (int mi = 0; mi < 4; ++mi)
        af[mi] = *(const short8*)(&As[wm * 64 + mi * 16 + l16][ks + quad * 8]);
#pragma unroll
      for (int ni = 0; ni < 4; ++ni)
        bfr[ni] = *(const short8*)(&Bs[wn * 64 + ni * 16 + l16][ks + quad * 8]);
#pragma unroll
      for (int mi = 0; mi < 4; ++mi)
#pragma unroll
        for (int ni = 0; ni < 4; ++ni)
          acc[mi][ni] = __builtin_amdgcn_mfma_f32_16x16x32_bf16(af[mi], bfr[ni],
                                                                acc[mi][ni], 0, 0, 0);
    }
    __syncthreads();
  }
  // C/D layout: row = quad*4 + r, col = lane&15
#pragma unroll
  for (int mi = 0; mi < 4; ++mi) {
#pragma unroll
    for (int r = 0; r < 4; ++r) {
      int grow = m0 + wm * 64 + mi * 16 + quad * 4 + r;
      if (grow >= M) continue;
#pragma unroll
      for (int ni = 0; ni < 4; ++ni) {
        int gcol = n0 + wn * 64 + ni * 16 + l16;
        C[(size_t)grow * N + gcol] = f2bu(acc[mi][ni][r] + biasc[gcol]);
      }
    }
  }
}

// ================= CSR build (counting sort by dst) =================
__global__ void hist_k(const int* __restrict__ dst, int* __restrict__ deg, int e) {
  int i = blockIdx.x * blockDim.x + threadIdx.x;
  if (i < e) atomicAdd(&deg[dst[i]], 1);
}

__global__ void scan_block_k(const int* __restrict__ deg, int* __restrict__ row_ptr,
                             int* __restrict__ bsum, int n) {
  __shared__ int s[1024];
  int i = blockIdx.x * 1024 + threadIdx.x;
  int v = (i < n) ? deg[i] : 0;
  s[threadIdx.x] = v;
  __syncthreads();
  for (int off = 1; off < 1024; off <<= 1) {
    int t = (threadIdx.x >= off) ? s[threadIdx.x - off] : 0;
    __syncthreads();
    s[threadIdx.x] += t;
    __syncthreads();
  }
  if (i < n) row_ptr[i + 1] = s[threadIdx.x];
  if (threadIdx.x == 1023) bsum[blockIdx.x] = s[1023];
}

__global__ void scan_bsum_k(int* __restrict__ bsum, int nb) {
  __shared__ int s[128];
  int v = (threadIdx.x < nb) ? bsum[threadIdx.x] : 0;
  s[threadIdx.x] = v;
  __syncthreads();
  for (int off = 1; off < 128; off <<= 1) {
    int t = (threadIdx.x >= off) ? s[threadIdx.x - off] : 0;
    __syncthreads();
    s[threadIdx.x] += t;
    __syncthreads();
  }
  if (threadIdx.x < nb) bsum[threadIdx.x] = s[threadIdx.x] - v;  // exclusive
}

// fused: finalize row_ptr AND write cursor (race-free: thread i writes
// row_ptr[i+1] and cursor[i+1] with the same value it computed locally)
__global__ void add_off_k(int* __restrict__ row_ptr, int* __restrict__ cursor,
                          const int* __restrict__ bsum, int n) {
  int i = blockIdx.x * blockDim.x + threadIdx.x;
  if (i == 0) { row_ptr[0] = 0; cursor[0] = 0; }
  if (i < n) {
    int v = row_ptr[i + 1] + bsum[i >> 10];
    row_ptr[i + 1] = v;
    if (i + 1 < n) cursor[i + 1] = v;
  }
}

__global__ void fill_k(const int* __restrict__ src, const int* __restrict__ dst,
                       const float* __restrict__ eattr, int* __restrict__ cursor,
                       int2* __restrict__ csr, int e) {
  int i = blockIdx.x * blockDim.x + threadIdx.x;
  if (i >= e) return;
  int p = atomicAdd(&cursor[dst[i]], 1);
  csr[p] = make_int2(src[i], __float_as_int(eattr[i]));
}

// ========== fused GATv2 layer 1: one wave per node, 4 ch/lane ==========
// C1 row: [xl(256) | xr(256)] bf16. lane L owns channels 4L..4L+3; head(4L)=L>>4.
// Edge loop: MASKED x4 batches (no scalar remainder) -> 4 gathers always in
// flight; out-of-range slots clamp to a valid edge and contribute exp()=0.
__global__ void gat1_k(const int* __restrict__ row_ptr, const int2* __restrict__ csr,
                       const ushort_t* __restrict__ C1,
                       const float* __restrict__ We, const float* __restrict__ att,
                       const float* __restrict__ bias, ushort_t* __restrict__ h1, int n) {
  int node = (int)(((size_t)blockIdx.x * blockDim.x + threadIdx.x) >> 6);
  int lane = threadIdx.x & 63;
  if (node >= n) return;
  int cb = lane * 4;
  ushort4v xr4 = *(const ushort4v*)(C1 + (size_t)node * 512 + 256 + cb);
  float xrr[4], Wev[4], attv[4], acc[4] = {0.f, 0.f, 0.f, 0.f};
  float esum = 0.f;
#pragma unroll
  for (int j = 0; j < 4; ++j) {
    xrr[j] = bu2f(xr4[j]);
    Wev[j] = We[cb + j];
    attv[j] = att[cb + j];
  }
  int p = row_ptr[node], p1 = row_ptr[node + 1];
  int pl = p1 - 1;
  for (int pb = p; pb < p1; pb += 4) {
    int2 ee[4];
#pragma unroll
    for (int u = 0; u < 4; ++u) {
      int q = pb + u;
      ee[u] = csr[q < p1 ? q : pl];
    }
    ushort4v xl4[4];
#pragma unroll
    for (int u = 0; u < 4; ++u)
      xl4[u] = *(const ushort4v*)(C1 + (size_t)ee[u].x * 512 + cb);
    float xv[4][4], v[4];
#pragma unroll
    for (int u = 0; u < 4; ++u) {
      float wgt = __int_as_float(ee[u].y);
      v[u] = 0.f;
#pragma unroll
      for (int j = 0; j < 4; ++j) {
        xv[u][j] = bu2f(xl4[u][j]);
        float m = xv[u][j] + xrr[j] + wgt * Wev[j];
        m = fmaxf(m, NEG * m);          // leaky_relu, slope<1: max(m, NEG*m)
        v[u] += m * attv[j];
      }
    }
#pragma unroll
    for (int u = 0; u < 4; ++u) {
      v[u] += __shfl_xor(v[u], 1, 64);
      v[u] += __shfl_xor(v[u], 2, 64);
      v[u] += __shfl_xor(v[u], 4, 64);
      v[u] += __shfl_xor(v[u], 8, 64);
    }
#pragma unroll
    for (int u = 0; u < 4; ++u) {
      float eh = (pb + u < p1) ? __expf(v[u]) : 0.f;   // mask invalid slots
      esum += eh;
#pragma unroll
      for (int j = 0; j < 4; ++j) acc[j] += eh * xv[u][j];
    }
  }
  float inv = 1.f / (esum + 1e-16f);
  ushort4v o;
#pragma unroll
  for (int j = 0; j < 4; ++j) {
    float t = acc[j] * inv + bias[cb + j];
    o[j] = f2bu(t > 0.f ? t : 0.f);   // fused relu
  }
  *(ushort4v*)(h1 + (size_t)node * D1 + cb) = o;
}

// ========== fused GATv2 layer 2: one wave per node, 8 parallel edge slots ==========
// 8-lane group g owns edge slot g (4 ch/lane x 8 lanes = 32 channels).
// Masked batch of 8 edges -> typically ONE iteration per node (Poisson(5) degrees),
// 8 gathers in flight, then a 3-step cross-group reduce.
__global__ void gat2_k(const int* __restrict__ row_ptr, const int2* __restrict__ csr,
                       const ushort_t* __restrict__ C2,
                       const float* __restrict__ We, const float* __restrict__ att,
                       const float* __restrict__ bias, float* __restrict__ out, int n) {
  int node = (int)(((size_t)blockIdx.x * blockDim.x + threadIdx.x) >> 6);
  int lane = threadIdx.x & 63;
  if (node >= n) return;
  int g = lane >> 3;          // edge slot 0..7
  int cb = (lane & 7) * 4;    // channel base 0..28
  ushort4v xr4 = *(const ushort4v*)(C2 + (size_t)node * 64 + 32 + cb);
  float xrr[4], Wev[4], attv[4], acc[4] = {0.f, 0.f, 0.f, 0.f};
  float esum = 0.f;
#pragma unroll
  for (int j = 0; j < 4; ++j) {
    xrr[j] = bu2f(xr4[j]);
    Wev[j] = We[cb + j];
    attv[j] = att[cb + j];
  }
  int p = row_ptr[node], p1 = row_ptr[node + 1];
  int pl = p1 - 1;
  for (int pb = p; pb < p1; pb += 8) {
    int q = pb + g;
    int2 ed = csr[q < p1 ? q : pl];
    float wgt = __int_as_float(ed.y);
    ushort4v xl4 = *(const ushort4v*)(C2 + (size_t)ed.x * 64 + cb);
    float xv[4], v = 0.f;
#pragma unroll
    for (int j = 0; j < 4; ++j) {
      xv[j] = bu2f(xl4[j]);
      float m = xv[j] + xrr[j] + wgt * Wev[j];
      m = fmaxf(m, NEG * m);
      v += m * attv[j];
    }
    v += __shfl_xor(v, 1, 64);
    v += __shfl_xor(v, 2, 64);
    v += __shfl_xor(v, 4, 64);
    float eh = (q < p1) ? __expf(v) : 0.f;
    esum += eh;
#pragma unroll
    for (int j = 0; j < 4; ++j) acc[j] += eh * xv[j];
  }
  // reduce across the 8 edge-slot groups
  esum += __shfl_xor(esum, 8, 64);
  esum += __shfl_xor(esum, 16, 64);
  esum += __shfl_xor(esum, 32, 64);
#pragma unroll
  for (int j = 0; j < 4; ++j) {
    acc[j] += __shfl_xor(acc[j], 8, 64);
    acc[j] += __shfl_xor(acc[j], 16, 64);
    acc[j] += __shfl_xor(acc[j], 32, 64);
  }
  if (lane < 8) {
    float inv = 1.f / (esum + 1e-16f);
    f32x4 ov;
#pragma unroll
    for (int j = 0; j < 4; ++j) ov[j] = acc[j] * inv + bias[cb + j];
    *(f32x4*)(out + (size_t)node * OUT_C + cb) = ov;
  }
}

extern "C" void kernel_launch(void* const* d_in, const int* in_sizes, int n_in,
                              void* d_out, int out_size, void* d_ws, size_t ws_size,
                              hipStream_t stream) {
  const float* x     = (const float*)d_in[0];
  const int*   eidx  = (const int*)d_in[1];
  const float* eattr = (const float*)d_in[2];
  const float* Wl1 = (const float*)d_in[3];
  const float* bl1 = (const float*)d_in[4];
  const float* Wr1 = (const float*)d_in[5];
  const float* br1 = (const float*)d_in[6];
  const float* We1 = (const float*)d_in[7];
  const float* att1 = (const float*)d_in[8];
  const float* b1  = (const float*)d_in[9];
  const float* Wl2 = (const float*)d_in[10];
  const float* bl2 = (const float*)d_in[11];
  const float* Wr2 = (const float*)d_in[12];
  const float* br2 = (const float*)d_in[13];
  const float* We2 = (const float*)d_in[14];
  const float* att2 = (const float*)d_in[15];
  const float* b2  = (const float*)d_in[16];

  const int n = in_sizes[0] / F_IN;   // 100000
  const int e = in_sizes[2];          // 500000
  const int* src = eidx;
  const int* dst = eidx + e;
  float* out = (float*)d_out;

  // ---- workspace (~171 MB) ----
  char* w = (char*)d_ws;
  ushort_t* C1   = (ushort_t*)w;  w += (size_t)n * 512 * 2;      // 102.4 MB
  ushort_t* h1b  = (ushort_t*)w;  w += (size_t)n * D1 * 2;       // 51.2 MB
  ushort_t* C2   = (ushort_t*)w;  w += (size_t)n * 64 * 2;       // 12.8 MB
  ushort_t* Bt1  = (ushort_t*)w;  w += 512 * F_IN * 2;
  ushort_t* Bt2  = (ushort_t*)w;  w += 64 * D1 * 2;
  float* bias1c  = (float*)w;     w += 512 * 4;
  float* bias2c  = (float*)w;     w += 64 * 4;
  int2*  csr     = (int2*)w;      w += (size_t)e * 8;
  int*   row_ptr = (int*)w;       w += ((size_t)n + 1) * 4;
  int*   cursor  = (int*)w;       w += (size_t)n * 4;
  int*   bsum    = (int*)w;       w += 512;
  int*   deg = cursor;            // disjoint lifetimes

  dim3 blk(256);
  const int nb = (n + 1023) / 1024;   // 98 <= 128
  const int nmt = (n + 127) / 128;    // 782 M-tiles

  // ---- prep: transpose+convert weights (both layers, one launch) ----
  prep_k<<<320, blk, 0, stream>>>(Wl1, Wr1, bl1, br1, Bt1, bias1c,
                                  Wl2, Wr2, bl2, br2, Bt2, bias2c);

  // ---- CSR build ----
  hipMemsetAsync(deg, 0, (size_t)n * sizeof(int), stream);
  hist_k<<<(e + 255) / 256, blk, 0, stream>>>(dst, deg, e);
  scan_block_k<<<nb, 1024, 0, stream>>>(deg, row_ptr, bsum, n);
  scan_bsum_k<<<1, 128, 0, stream>>>(bsum, nb);
  add_off_k<<<(n + 255) / 256, blk, 0, stream>>>(row_ptr, cursor, bsum, n);
  fill_k<<<(e + 255) / 256, blk, 0, stream>>>(src, dst, eattr, cursor, csr, e);

  // ---- layer 1: C1 = x @ [Wl1|Wr1] + bias  (n x 128 @ 128 x 512) ----
  gemm1_k<<<nmt, blk, 0, stream>>>(x, Bt1, bias1c, C1, n);
  gat1_k<<<(n + 3) / 4, blk, 0, stream>>>(row_ptr, csr, C1, We1, att1, b1, h1b, n);

  // ---- layer 2: C2 = h1 @ [Wl2|Wr2] + bias  (n x 256 @ 256 x 64) ----
  mfma_gemm<2, 1, 64, false><<<dim3(nmt, 1), dim3(128), 0, stream>>>(
      h1b, Bt2, bias2c, C2, n, 64, D1);
  gat2_k<<<(n + 3) / 4, blk, 0, stream>>>(row_ptr, csr, C2, We2, att2, b2, out, n);
}